// Round 14
// baseline (103.926 us; speedup 1.0000x reference)
//
#include <hip/hip_runtime.h>
#include <hip/hip_fp16.h>

typedef float f2v __attribute__((ext_vector_type(2)));
typedef float f4v __attribute__((ext_vector_type(4)));

// 24B packed row: 10 x f16 (20B) + 4B pad, 8B-aligned. As table = 2.4MB.
struct __attribute__((packed, aligned(8))) Row24 {
    uint2 ab;   // h0..h3
    uint2 cd;   // h4..h7
    uint  e;    // h8..h9
    uint  pad;
};

__device__ __forceinline__ float2 h2f2(uint v) {
    __half2 h = *(__half2*)&v;
    return __half22float2(h);
}

// ---- prep: A_s[n] = x_s[n] @ W1[0:10,:]  -> f16 Row24 (2.4 MB) ----
__global__ __launch_bounds__(256) void prep_as(const float* __restrict__ xs,
                                               const float* __restrict__ W1,
                                               Row24* __restrict__ As, int N) {
    const int n = blockIdx.x * 256 + threadIdx.x;
    if (n >= N) return;
    float f[10];
    const float2* p = (const float2*)(xs + (size_t)n * 10);
    #pragma unroll
    for (int i = 0; i < 5; ++i) { float2 v = p[i]; f[2 * i] = v.x; f[2 * i + 1] = v.y; }
    float a[10];
    #pragma unroll
    for (int j = 0; j < 10; ++j) a[j] = 0.f;
    #pragma unroll
    for (int k = 0; k < 10; ++k) {
        const float fk = f[k];
        #pragma unroll
        for (int j = 0; j < 10; ++j) a[j] += fk * W1[k * 10 + j];   // uniform -> s_load
    }
    uint q[5];
    #pragma unroll
    for (int i = 0; i < 5; ++i) {
        __half2 h = __floats2half2_rn(a[2 * i], a[2 * i + 1]);
        q[i] = *(uint*)&h;
    }
    Row24 r;
    r.ab = make_uint2(q[0], q[1]);
    r.cd = make_uint2(q[2], q[3]);
    r.e  = q[4];
    r.pad = 0;
    As[n] = r;
}

// ---- prep: x_t[n] -> 5 x f16 packed into 16B (one dwordx4 gather; 1.6 MB) ----
__global__ __launch_bounds__(256) void prep_xt(const float* __restrict__ xt,
                                               uint4* __restrict__ Xt, int N) {
    const int n = blockIdx.x * 256 + threadIdx.x;
    if (n >= N) return;
    float f[5];
    #pragma unroll
    for (int i = 0; i < 5; ++i) f[i] = xt[(size_t)n * 5 + i];
    __half2 h01 = __floats2half2_rn(f[0], f[1]);
    __half2 h23 = __floats2half2_rn(f[2], f[3]);
    __half2 h4_ = __floats2half2_rn(f[4], 0.f);
    uint4 r;
    r.x = *(uint*)&h01;
    r.y = *(uint*)&h23;
    r.z = *(uint*)&h4_;
    r.w = 0;
    Xt[n] = r;
}

// shared per-edge MLP tail (forceinline; all indices compile-time)
__device__ __forceinline__ void mlp_edge(const float* __restrict__ g,   // 10 ea values
                                         Row24 ra, uint4 rt, int ib,
                                         const float* __restrict__ sUp,
                                         const float* __restrict__ W1,
                                         const float* __restrict__ W2,
                                         const float* __restrict__ b2,
                                         float* __restrict__ o)        // 10 outputs
{
    float h[10];
    {
        uint qa[5] = { ra.ab.x, ra.ab.y, ra.cd.x, ra.cd.y, ra.e };
        #pragma unroll
        for (int i = 0; i < 5; ++i) {
            float2 a2 = h2f2(qa[i]);
            h[2 * i]     = a2.x + sUp[ib * 12 + 2 * i];
            h[2 * i + 1] = a2.y + sUp[ib * 12 + 2 * i + 1];
        }
    }
    {
        float2 t01 = h2f2(rt.x), t23 = h2f2(rt.y), t4_ = h2f2(rt.z);
        const float tv[5] = { t01.x, t01.y, t23.x, t23.y, t4_.x };
        #pragma unroll
        for (int k = 0; k < 5; ++k) {
            const float fk = tv[k];
            #pragma unroll
            for (int j = 0; j < 10; ++j) h[j] += fk * W1[(10 + k) * 10 + j];
        }
    }
    #pragma unroll
    for (int k = 0; k < 10; ++k) {
        const float gk = g[k];
        #pragma unroll
        for (int j = 0; j < 10; ++j) h[j] += gk * W1[(15 + k) * 10 + j];
    }
    #pragma unroll
    for (int j = 0; j < 10; ++j) h[j] = (h[j] >= 0.f) ? h[j] : 0.1f * h[j];

    #pragma unroll
    for (int j = 0; j < 10; ++j) o[j] = b2[j];
    #pragma unroll
    for (int k = 0; k < 10; ++k) {
        const float hk = h[k];
        #pragma unroll
        for (int j = 0; j < 10; ++j) o[j] += hk * W2[k * 10 + j];
    }
}

// ---- main: r12 structure with front-end reorder — idx first, stage second,
//      gathers third, ONE drain barrier. All latency chains overlap. ----
__global__ __launch_bounds__(256) void edge_mlp_stage(
    const Row24* __restrict__ As,
    const uint4* __restrict__ Xt,
    const int* __restrict__ src,
    const int* __restrict__ tgt,
    const float* __restrict__ ea,
    const float* __restrict__ u,
    const int* __restrict__ be,
    const float* __restrict__ W1,
    const float* __restrict__ b1,
    const float* __restrict__ W2,
    const float* __restrict__ b2,
    float* __restrict__ out, int E)
{
    __shared__ float sUp[16 * 12];    // U' = u @ W1[25:35] + b1
    __shared__ __align__(16) float stage[2560];   // 256 edges x 10 floats: ea in, out later

    const int t = threadIdx.x;
    const int  base_e = blockIdx.x * 256;
    const long long base_f = (long long)base_e * 10;
    const bool full = (base_e + 256) <= E;
    const int e = base_e + t;
    const bool valid = e < E;
    const int ec = valid ? e : (E - 1);   // clamped index for branch-free loads

    // ---- 1. idx NT loads FIRST (start the dependent gather chain) ----
    const int is = __builtin_nontemporal_load(src + ec);
    const int it = __builtin_nontemporal_load(tgt + ec);
    const int ib = __builtin_nontemporal_load(be + ec);

    // ---- 2. sUp compute (independent loads, overlap) ----
    if (t < 160) {
        const int b = t / 10, j = t % 10;
        float acc = b1[j];
        #pragma unroll
        for (int k = 0; k < 10; ++k) acc += u[b * 10 + k] * W1[(25 + k) * 10 + j];
        sUp[b * 12 + j] = acc;
    }

    // ---- 3. stage-in ea: cooperative NT dwordx4 (independent of idx) ----
    if (full) {
        const f4v* pe = (const f4v*)(ea + base_f);
        #pragma unroll
        for (int r = 0; r < 3; ++r) {
            int i = t + r * 256;
            if (i < 640) ((f4v*)stage)[i] = __builtin_nontemporal_load(pe + i);
        }
    } else {
        const long long totalf = (long long)E * 10;
        for (int i = t; i < 2560; i += 256)
            if (base_f + i < totalf) stage[i] = ea[base_f + i];
    }

    // ---- 4. table gathers (wait only on idx; overlap with stage + barrier) ----
    Row24 ra = As[is];            // dwordx4 + dwordx2, L2-resident table
    uint4 rt = Xt[it];            // dwordx4, L2-resident table

    // ---- 5. ONE drain: stage + sUp + gathers all complete here ----
    __syncthreads();

    float o[10];
    if (valid) {
        float g[10];
        const f2v* pg = (const f2v*)&stage[t * 10];   // own row, 8B-aligned
        #pragma unroll
        for (int i = 0; i < 5; ++i) { f2v v = pg[i]; g[2 * i] = v[0]; g[2 * i + 1] = v[1]; }
        mlp_edge(g, ra, rt, ib, sUp, W1, W2, b2, o);
    }

    if (full) {
        // own-row write (thread t reads/writes only row t: no cross-thread hazard)
        #pragma unroll
        for (int i = 0; i < 5; ++i) {
            f2v v; v[0] = o[2 * i]; v[1] = o[2 * i + 1];
            *(f2v*)&stage[t * 10 + 2 * i] = v;
        }
        __syncthreads();   // o-rows visible to all before cooperative store
        const f4v* sp = (const f4v*)stage;
        f4v* po = (f4v*)(out + base_f);
        po[t] = sp[t];
        po[t + 256] = sp[t + 256];
        if (t < 128) po[t + 512] = sp[t + 512];
    } else if (valid) {
        float2* po = (float2*)(out + (size_t)e * 10);
        #pragma unroll
        for (int i = 0; i < 5; ++i) { float2 v; v.x = o[2 * i]; v.y = o[2 * i + 1]; po[i] = v; }
    }
}

// ---- fallback (ws too small): direct compute from raw tables ----
__global__ __launch_bounds__(256) void edge_mlp_raw(
    const float* __restrict__ xs, const float* __restrict__ xt,
    const int* __restrict__ src, const int* __restrict__ tgt,
    const float* __restrict__ ea, const float* __restrict__ u,
    const int* __restrict__ be,
    const float* __restrict__ W1, const float* __restrict__ b1,
    const float* __restrict__ W2, const float* __restrict__ b2,
    float* __restrict__ out, int E)
{
    __shared__ float sUp[16 * 12];
    const int t = threadIdx.x;
    if (t < 160) {
        const int b = t / 10, j = t % 10;
        float acc = b1[j];
        #pragma unroll
        for (int k = 0; k < 10; ++k) acc += u[b * 10 + k] * W1[(25 + k) * 10 + j];
        sUp[b * 12 + j] = acc;
    }
    __syncthreads();
    const int e = blockIdx.x * 256 + t;
    if (e >= E) return;
    const int is = src[e], it = tgt[e], ib = be[e];
    float f[25];
    const float* ps = xs + (size_t)is * 10;
    #pragma unroll
    for (int i = 0; i < 5; ++i) {
        float2 v = *(const float2*)(ps + 2 * i);
        f[2 * i] = v.x; f[2 * i + 1] = v.y;
    }
    const float* pt = xt + (size_t)it * 5;
    #pragma unroll
    for (int i = 0; i < 5; ++i) f[10 + i] = pt[i];
    const float2* pe = (const float2*)(ea + (size_t)e * 10);
    #pragma unroll
    for (int i = 0; i < 5; ++i) { float2 v = pe[i]; f[15 + 2 * i] = v.x; f[16 + 2 * i] = v.y; }
    float h[10];
    #pragma unroll
    for (int j = 0; j < 10; ++j) h[j] = sUp[ib * 12 + j];
    #pragma unroll
    for (int k = 0; k < 25; ++k) {
        const float fk = f[k];
        #pragma unroll
        for (int j = 0; j < 10; ++j) h[j] += fk * W1[k * 10 + j];
    }
    #pragma unroll
    for (int j = 0; j < 10; ++j) h[j] = (h[j] >= 0.f) ? h[j] : 0.1f * h[j];
    float o[10];
    #pragma unroll
    for (int j = 0; j < 10; ++j) o[j] = b2[j];
    #pragma unroll
    for (int k = 0; k < 10; ++k) {
        const float hk = h[k];
        #pragma unroll
        for (int j = 0; j < 10; ++j) o[j] += hk * W2[k * 10 + j];
    }
    float2* po = (float2*)(out + (size_t)e * 10);
    #pragma unroll
    for (int i = 0; i < 5; ++i) { float2 v; v.x = o[2 * i]; v.y = o[2 * i + 1]; po[i] = v; }
}

extern "C" void kernel_launch(void* const* d_in, const int* in_sizes, int n_in,
                              void* d_out, int out_size, void* d_ws, size_t ws_size,
                              hipStream_t stream) {
    const float* x_s      = (const float*)d_in[0];
    const float* x_t      = (const float*)d_in[1];
    const int*   ei       = (const int*)d_in[2];    // (2, E) flat: [src | tgt]
    const float* edge_att = (const float*)d_in[3];
    const float* u        = (const float*)d_in[4];
    const int*   batch_e  = (const int*)d_in[5];
    const float* W1       = (const float*)d_in[6];
    const float* b1       = (const float*)d_in[7];
    const float* W2       = (const float*)d_in[8];
    const float* b2       = (const float*)d_in[9];
    float* out = (float*)d_out;

    const int E   = in_sizes[5];
    const int N_S = in_sizes[0] / 10;
    const int N_T = in_sizes[1] / 5;
    const int blocks = (E + 255) / 256;

    const size_t need = (size_t)N_S * sizeof(Row24) + (size_t)N_T * sizeof(uint4);
    if (ws_size >= need) {
        Row24* As = (Row24*)d_ws;
        uint4* Xt = (uint4*)((char*)d_ws + (size_t)N_S * sizeof(Row24));
        prep_as<<<(N_S + 255) / 256, 256, 0, stream>>>(x_s, W1, As, N_S);
        prep_xt<<<(N_T + 255) / 256, 256, 0, stream>>>(x_t, Xt, N_T);
        edge_mlp_stage<<<blocks, 256, 0, stream>>>(
            As, Xt, ei, ei + E, edge_att, u, batch_e,
            W1, b1, W2, b2, out, E);
    } else {
        edge_mlp_raw<<<blocks, 256, 0, stream>>>(
            x_s, x_t, ei, ei + E, edge_att, u, batch_e,
            W1, b1, W2, b2, out, E);
    }
}